// Round 1
// baseline (345.057 us; speedup 1.0000x reference)
//
#include <hip/hip_runtime.h>
#include <hip/hip_bf16.h>
#include <math.h>

// ---- problem constants ----
#define BROWS 16384
#define NF    10
#define EMB   32
#define DENSE 16
#define K0    336   // 10*32 + 16
#define N0    256
#define N1    128
#define N2    64
#define BN_INV 0.99999500003749969f  // 1/sqrt(1+1e-5)

__constant__ int c_offsets[NF] = {
    0, 1000000, 1100000, 1101008, 1102012,
    1102114, 1103114, 1103614, 1103664, 1103776
};

// ---------------------------------------------------------------------------
// Kernel 1: embedding gather + FM (first & second order) + build x0 [B, 336]
// one thread per batch row
// ---------------------------------------------------------------------------
__global__ __launch_bounds__(256) void k_build_x(
    const int* __restrict__ sparse,      // [B, NF] int32
    const float* __restrict__ dense,     // [B, DENSE]
    const float* __restrict__ emb,       // [V, EMB]
    const float* __restrict__ bias_tab,  // [V]
    const float* __restrict__ fm_bias,   // [1]
    float* __restrict__ x0,              // [B, K0]
    float* __restrict__ fm)              // [B]
{
    int row = blockIdx.x * 256 + threadIdx.x;
    if (row >= BROWS) return;

    float s[EMB];
#pragma unroll
    for (int d = 0; d < EMB; ++d) s[d] = 0.f;
    float sq = 0.f;      // sum over fields and dims of e^2
    float first = 0.f;

    float* xr = x0 + (size_t)row * K0;

#pragma unroll
    for (int f = 0; f < NF; ++f) {
        int idx = sparse[row * NF + f] + c_offsets[f];
        first += bias_tab[idx];
        const float4* er = (const float4*)(emb + (size_t)idx * EMB);
#pragma unroll
        for (int q = 0; q < EMB / 4; ++q) {
            float4 v = er[q];
            int base = f * EMB + 4 * q;
            xr[base + 0] = v.x; xr[base + 1] = v.y;
            xr[base + 2] = v.z; xr[base + 3] = v.w;
            s[4 * q + 0] += v.x; s[4 * q + 1] += v.y;
            s[4 * q + 2] += v.z; s[4 * q + 3] += v.w;
            sq += v.x * v.x + v.y * v.y + v.z * v.z + v.w * v.w;
        }
    }

    float ssum = 0.f;
#pragma unroll
    for (int d = 0; d < EMB; ++d) ssum += s[d] * s[d];
    float second = 0.5f * (ssum - sq);

    // dense tail
#pragma unroll
    for (int k = 0; k < DENSE; ++k)
        xr[NF * EMB + k] = dense[row * DENSE + k];

    fm[row] = fm_bias[0] + first + second;
}

// ---------------------------------------------------------------------------
// Kernels 2-4: C[M,N] = relu( (A[M,K] @ W[N,K]^T + b) * (g*inv) + be )
// 64x64 tile, 256 threads, 4x4 accumulators/thread, LDS-staged, K%16==0
// ---------------------------------------------------------------------------
template <int N, int K>
__global__ __launch_bounds__(256) void k_gemm_bn_relu(
    const float* __restrict__ A,
    const float* __restrict__ W,
    const float* __restrict__ b,
    const float* __restrict__ g,
    const float* __restrict__ be,
    float* __restrict__ C)
{
    __shared__ float As[16][65];
    __shared__ float Bs[16][65];

    const int tid = threadIdx.x;
    const int tx = tid & 15;        // n sub-tile
    const int ty = tid >> 4;        // m sub-tile
    const int bm = blockIdx.x * 64;
    const int bn = blockIdx.y * 64;

    const int lc = tid & 15;        // k within tile (load)
    const int lr = tid >> 4;        // row base (load)

    float acc[4][4];
#pragma unroll
    for (int i = 0; i < 4; ++i)
#pragma unroll
        for (int j = 0; j < 4; ++j) acc[i][j] = 0.f;

    for (int k0 = 0; k0 < K; k0 += 16) {
#pragma unroll
        for (int i = 0; i < 4; ++i) {
            int r = lr + 16 * i;
            As[lc][r] = A[(size_t)(bm + r) * K + k0 + lc];
            Bs[lc][r] = W[(size_t)(bn + r) * K + k0 + lc];
        }
        __syncthreads();
#pragma unroll
        for (int k = 0; k < 16; ++k) {
            float a[4], w[4];
#pragma unroll
            for (int i = 0; i < 4; ++i) a[i] = As[k][ty * 4 + i];
#pragma unroll
            for (int j = 0; j < 4; ++j) w[j] = Bs[k][tx * 4 + j];
#pragma unroll
            for (int i = 0; i < 4; ++i)
#pragma unroll
                for (int j = 0; j < 4; ++j)
                    acc[i][j] = fmaf(a[i], w[j], acc[i][j]);
        }
        __syncthreads();
    }

#pragma unroll
    for (int j = 0; j < 4; ++j) {
        int o = bn + tx * 4 + j;
        float sc = g[o] * BN_INV;
        float tb = fmaf(b[o], sc, be[o]);
#pragma unroll
        for (int i = 0; i < 4; ++i) {
            float v = fmaf(acc[i][j], sc, tb);
            v = v > 0.f ? v : 0.f;
            C[(size_t)(bm + ty * 4 + i) * N + o] = v;
        }
    }
}

// ---------------------------------------------------------------------------
// Kernel 5: out = sigmoid(fm + x3 @ Wo^T + bo)   (one thread per row)
// ---------------------------------------------------------------------------
__global__ __launch_bounds__(256) void k_final(
    const float* __restrict__ x3,   // [B, 64]
    const float* __restrict__ Wo,   // [64]
    const float* __restrict__ bo,   // [1]
    const float* __restrict__ fm,   // [B]
    float* __restrict__ out)        // [B]
{
    int row = blockIdx.x * 256 + threadIdx.x;
    if (row >= BROWS) return;
    const float4* xr = (const float4*)(x3 + (size_t)row * 64);
    const float4* wr = (const float4*)Wo;
    float dot = 0.f;
#pragma unroll
    for (int q = 0; q < 16; ++q) {
        float4 a = xr[q];
        float4 w = wr[q];
        dot += a.x * w.x + a.y * w.y + a.z * w.z + a.w * w.w;
    }
    float z = fm[row] + dot + bo[0];
    out[row] = 1.f / (1.f + expf(-z));
}

// ---------------------------------------------------------------------------
extern "C" void kernel_launch(void* const* d_in, const int* in_sizes, int n_in,
                              void* d_out, int out_size, void* d_ws, size_t ws_size,
                              hipStream_t stream)
{
    const int*   sparse   = (const int*)  d_in[0];
    const float* dense    = (const float*)d_in[1];
    const float* emb      = (const float*)d_in[2];
    const float* bias_tab = (const float*)d_in[3];
    const float* fm_bias  = (const float*)d_in[4];
    const float* Wo       = (const float*)d_in[5];
    const float* bo       = (const float*)d_in[6];
    const float* W0 = (const float*)d_in[7];
    const float* b0 = (const float*)d_in[8];
    const float* g0 = (const float*)d_in[9];
    const float* be0= (const float*)d_in[10];
    const float* W1 = (const float*)d_in[11];
    const float* b1 = (const float*)d_in[12];
    const float* g1 = (const float*)d_in[13];
    const float* be1= (const float*)d_in[14];
    const float* W2 = (const float*)d_in[15];
    const float* b2 = (const float*)d_in[16];
    const float* g2 = (const float*)d_in[17];
    const float* be2= (const float*)d_in[18];

    float* out = (float*)d_out;

    // workspace layout (floats)
    float* x0 = (float*)d_ws;                       // [B, 336]
    float* x1 = x0 + (size_t)BROWS * K0;            // [B, 256]
    float* x2 = x1 + (size_t)BROWS * N0;            // [B, 128]
    float* x3 = x2 + (size_t)BROWS * N1;            // [B, 64]
    float* fm = x3 + (size_t)BROWS * N2;            // [B]

    k_build_x<<<BROWS / 256, 256, 0, stream>>>(sparse, dense, emb, bias_tab,
                                               fm_bias, x0, fm);

    dim3 g0d(BROWS / 64, N0 / 64);
    k_gemm_bn_relu<N0, K0><<<g0d, 256, 0, stream>>>(x0, W0, b0, g0, be0, x1);

    dim3 g1d(BROWS / 64, N1 / 64);
    k_gemm_bn_relu<N1, N0><<<g1d, 256, 0, stream>>>(x1, W1, b1, g1, be1, x2);

    dim3 g2d(BROWS / 64, N2 / 64);
    k_gemm_bn_relu<N2, N1><<<g2d, 256, 0, stream>>>(x2, W2, b2, g2, be2, x3);

    k_final<<<BROWS / 256, 256, 0, stream>>>(x3, Wo, bo, fm, out);
}

// Round 2
// 244.488 us; speedup vs baseline: 1.4113x; 1.4113x over previous
//
#include <hip/hip_runtime.h>
#include <hip/hip_bf16.h>
#include <math.h>

// ---- problem constants ----
#define BROWS 16384
#define NF    10
#define EMB   32
#define DENSE 16
#define K0S   352   // 336 padded to multiple of 32 (10*32+16 -> 11 K-steps)
#define K0    336
#define N0    256
#define N1    128
#define N2    64
#define BN_INV 0.99999500003749969f  // 1/sqrt(1+1e-5)

__constant__ int c_offsets[NF] = {
    0, 1000000, 1100000, 1101008, 1102012,
    1102114, 1103114, 1103614, 1103664, 1103776
};

typedef short  bf16x8 __attribute__((ext_vector_type(8)));
typedef float  f32x4  __attribute__((ext_vector_type(4)));

static __device__ __forceinline__ unsigned short f2bf(float x) {
    union { float f; unsigned u; } c; c.f = x;
    unsigned r = (c.u + 0x7FFFu + ((c.u >> 16) & 1u)) >> 16;  // RNE
    return (unsigned short)r;
}
static __device__ __forceinline__ float bf2f(unsigned short u) {
    union { unsigned u; float f; } c; c.u = ((unsigned)u) << 16; return c.f;
}

// ---------------------------------------------------------------------------
// Kernel 1: embedding gather -> x0 (bf16, K-padded) + FM first/second (fp32)
// 8 lanes per batch row; per field, the 8 lanes read the 128B embedding row.
// ---------------------------------------------------------------------------
__global__ __launch_bounds__(256) void k_gather_fm(
    const int*   __restrict__ sparse,    // [B, NF]
    const float* __restrict__ dense,     // [B, DENSE]
    const float* __restrict__ emb,       // [V, EMB]
    const float* __restrict__ bias_tab,  // [V]
    const float* __restrict__ fm_bias,   // [1]
    unsigned short* __restrict__ x0,     // [B, K0S] bf16 bits
    float* __restrict__ fm)              // [B]
{
    int gt  = blockIdx.x * 256 + threadIdx.x;
    int row = gt >> 3;
    int l   = gt & 7;
    if (row >= BROWS) return;

    const float4* emb4 = (const float4*)emb;
    unsigned short* xr = x0 + (size_t)row * K0S;

    float4 s4 = make_float4(0.f, 0.f, 0.f, 0.f);
    float sq = 0.f, first = 0.f;

#pragma unroll
    for (int f = 0; f < NF; ++f) {
        int idx = sparse[row * NF + f] + c_offsets[f];
        float4 v = emb4[(size_t)idx * 8 + l];
        s4.x += v.x; s4.y += v.y; s4.z += v.z; s4.w += v.w;
        sq += v.x * v.x + v.y * v.y + v.z * v.z + v.w * v.w;
        if (l == 0) first += bias_tab[idx];
        ushort4 o;
        o.x = f2bf(v.x); o.y = f2bf(v.y); o.z = f2bf(v.z); o.w = f2bf(v.w);
        *(ushort4*)(xr + f * EMB + 4 * l) = o;
    }

    float ss = s4.x * s4.x + s4.y * s4.y + s4.z * s4.z + s4.w * s4.w;
#pragma unroll
    for (int off = 1; off < 8; off <<= 1) {
        ss += __shfl_xor(ss, off, 8);
        sq += __shfl_xor(sq, off, 8);
    }

    if (l < 4) {  // dense tail cols [320,336)
        float4 dv = ((const float4*)dense)[row * 4 + l];
        ushort4 o;
        o.x = f2bf(dv.x); o.y = f2bf(dv.y); o.z = f2bf(dv.z); o.w = f2bf(dv.w);
        *(ushort4*)(xr + NF * EMB + 4 * l) = o;
    } else {      // zero pad cols [336,352)
        ushort4 z = make_ushort4(0, 0, 0, 0);
        *(ushort4*)(xr + K0 + 4 * (l - 4)) = z;
    }

    if (l == 0) fm[row] = fm_bias[0] + first + 0.5f * (ss - sq);
}

// ---------------------------------------------------------------------------
// Weight fp32 -> bf16 (+ K padding with zeros)
// ---------------------------------------------------------------------------
template <int NR, int KSRC, int KDST>
__global__ __launch_bounds__(256) void k_wconv(
    const float* __restrict__ src, unsigned short* __restrict__ dst)
{
    int i = blockIdx.x * 256 + threadIdx.x;
    if (i >= NR * KDST) return;
    int r = i / KDST, c = i - r * KDST;
    float v = (c < KSRC) ? src[r * KSRC + c] : 0.f;
    dst[i] = f2bf(v);
}

// ---------------------------------------------------------------------------
// MFMA GEMM: C[M,N] = relu((A @ W^T + b) * g*inv + be), bf16 in/out, fp32 acc
// block = 256 thr = 4 waves; block tile 128(M) x 64(N); wave = 32x64
// mfma_f32_16x16x32_bf16: A[m=lane&15][k=quad*8+j], B[k=quad*8+j][n=lane&15]
// (B = W^T so B-frag = W[n=lane&15][k=quad*8+j], same indexing as A)
// C/D: col=lane&15, row=quad*4+reg
// ---------------------------------------------------------------------------
template <int NOUT, int KS>
__global__ __launch_bounds__(256) void k_mfma_bn_relu(
    const unsigned short* __restrict__ A,   // [M, KS] bf16
    const unsigned short* __restrict__ W,   // [NOUT, KS] bf16
    const float* __restrict__ b,
    const float* __restrict__ g,
    const float* __restrict__ be,
    unsigned short* __restrict__ C)         // [M, NOUT] bf16
{
    const int tid  = threadIdx.x;
    const int wave = tid >> 6;
    const int lane = tid & 63;
    const int l16  = lane & 15;
    const int quad = lane >> 4;
    const int bm   = blockIdx.x * 128;
    const int bn   = blockIdx.y * 64;

    f32x4 acc[2][4];
#pragma unroll
    for (int i = 0; i < 2; ++i)
#pragma unroll
        for (int j = 0; j < 4; ++j) acc[i][j] = (f32x4){0.f, 0.f, 0.f, 0.f};

    const unsigned short* ap0 = A + (size_t)(bm + wave * 32 + l16) * KS + quad * 8;
    const unsigned short* ap1 = ap0 + (size_t)16 * KS;
    const unsigned short* wp0 = W + (size_t)(bn + l16) * KS + quad * 8;

#pragma unroll 1
    for (int k0 = 0; k0 < KS; k0 += 32) {
        bf16x8 a0 = *(const bf16x8*)(ap0 + k0);
        bf16x8 a1 = *(const bf16x8*)(ap1 + k0);
#pragma unroll
        for (int nt = 0; nt < 4; ++nt) {
            bf16x8 bw = *(const bf16x8*)(wp0 + (size_t)(16 * nt) * KS + k0);
            acc[0][nt] = __builtin_amdgcn_mfma_f32_16x16x32_bf16(a0, bw, acc[0][nt], 0, 0, 0);
            acc[1][nt] = __builtin_amdgcn_mfma_f32_16x16x32_bf16(a1, bw, acc[1][nt], 0, 0, 0);
        }
    }

#pragma unroll
    for (int nt = 0; nt < 4; ++nt) {
        int col = bn + 16 * nt + l16;
        float sc = g[col] * BN_INV;
        float tb = fmaf(b[col], sc, be[col]);
#pragma unroll
        for (int mt = 0; mt < 2; ++mt) {
#pragma unroll
            for (int r = 0; r < 4; ++r) {
                int row = bm + wave * 32 + 16 * mt + quad * 4 + r;
                float v = fmaf(acc[mt][nt][r], sc, tb);
                v = v > 0.f ? v : 0.f;
                C[(size_t)row * NOUT + col] = f2bf(v);
            }
        }
    }
}

// ---------------------------------------------------------------------------
// Final: out = sigmoid(fm + x3 @ Wo^T + bo)
// ---------------------------------------------------------------------------
__global__ __launch_bounds__(256) void k_final(
    const unsigned short* __restrict__ x3,  // [B, 64] bf16
    const float* __restrict__ Wo,           // [64]
    const float* __restrict__ bo,           // [1]
    const float* __restrict__ fm,           // [B]
    float* __restrict__ out)                // [B]
{
    int row = blockIdx.x * 256 + threadIdx.x;
    if (row >= BROWS) return;
    const uint4* xq = (const uint4*)(x3 + (size_t)row * 64);
    float dot = 0.f;
#pragma unroll
    for (int q = 0; q < 8; ++q) {
        uint4 v = xq[q];
        const float* w = Wo + 8 * q;
        dot += bf2f(v.x & 0xFFFFu) * w[0] + bf2f(v.x >> 16) * w[1];
        dot += bf2f(v.y & 0xFFFFu) * w[2] + bf2f(v.y >> 16) * w[3];
        dot += bf2f(v.z & 0xFFFFu) * w[4] + bf2f(v.z >> 16) * w[5];
        dot += bf2f(v.w & 0xFFFFu) * w[6] + bf2f(v.w >> 16) * w[7];
    }
    float z = fm[row] + dot + bo[0];
    out[row] = 1.f / (1.f + expf(-z));
}

// ---------------------------------------------------------------------------
extern "C" void kernel_launch(void* const* d_in, const int* in_sizes, int n_in,
                              void* d_out, int out_size, void* d_ws, size_t ws_size,
                              hipStream_t stream)
{
    const int*   sparse   = (const int*)  d_in[0];
    const float* dense    = (const float*)d_in[1];
    const float* emb      = (const float*)d_in[2];
    const float* bias_tab = (const float*)d_in[3];
    const float* fm_bias  = (const float*)d_in[4];
    const float* Wo       = (const float*)d_in[5];
    const float* bo       = (const float*)d_in[6];
    const float* W0 = (const float*)d_in[7];
    const float* b0 = (const float*)d_in[8];
    const float* g0 = (const float*)d_in[9];
    const float* be0= (const float*)d_in[10];
    const float* W1 = (const float*)d_in[11];
    const float* b1 = (const float*)d_in[12];
    const float* g1 = (const float*)d_in[13];
    const float* be1= (const float*)d_in[14];
    const float* W2 = (const float*)d_in[15];
    const float* b2 = (const float*)d_in[16];
    const float* g2 = (const float*)d_in[17];
    const float* be2= (const float*)d_in[18];

    float* out = (float*)d_out;

    // workspace layout (all 16B-aligned)
    char* p = (char*)d_ws;
    unsigned short* x0  = (unsigned short*)p; p += (size_t)BROWS * K0S * 2;  // 11.5 MB
    unsigned short* x1  = (unsigned short*)p; p += (size_t)BROWS * N0 * 2;   // 8 MB
    unsigned short* x2  = (unsigned short*)p; p += (size_t)BROWS * N1 * 2;   // 4 MB
    unsigned short* x3  = (unsigned short*)p; p += (size_t)BROWS * N2 * 2;   // 2 MB
    unsigned short* W0b = (unsigned short*)p; p += (size_t)N0 * K0S * 2;
    unsigned short* W1b = (unsigned short*)p; p += (size_t)N1 * N0 * 2;
    unsigned short* W2b = (unsigned short*)p; p += (size_t)N2 * N1 * 2;
    float*          fm  = (float*)p;

    // weight conversions (tiny)
    k_wconv<N0, K0, K0S><<<(N0 * K0S + 255) / 256, 256, 0, stream>>>(W0, W0b);
    k_wconv<N1, N0, N0 ><<<(N1 * N0  + 255) / 256, 256, 0, stream>>>(W1, W1b);
    k_wconv<N2, N1, N1 ><<<(N2 * N1  + 255) / 256, 256, 0, stream>>>(W2, W2b);

    // gather + FM + x0 build
    k_gather_fm<<<(BROWS * 8) / 256, 256, 0, stream>>>(
        sparse, dense, emb, bias_tab, fm_bias, x0, fm);

    // MLP layers (MFMA bf16)
    dim3 g0d(BROWS / 128, N0 / 64);
    k_mfma_bn_relu<N0, K0S><<<g0d, 256, 0, stream>>>(x0, W0b, b0, g0, be0, x1);
    dim3 g1d(BROWS / 128, N1 / 64);
    k_mfma_bn_relu<N1, N0 ><<<g1d, 256, 0, stream>>>(x1, W1b, b1, g1, be1, x2);
    dim3 g2d(BROWS / 128, N2 / 64);
    k_mfma_bn_relu<N2, N1 ><<<g2d, 256, 0, stream>>>(x2, W2b, b2, g2, be2, x3);

    k_final<<<BROWS / 256, 256, 0, stream>>>(x3, Wo, bo, fm, out);
}